// Round 1
// baseline (119.780 us; speedup 1.0000x reference)
//
#include <hip/hip_runtime.h>

// NWJ lower bound:
//   T1[i,j] = sum_k relu(xp[j,k] + yp[i,k] + b1[k]) * W2[k] + b2 - 1
//   bound   = mean_i T0[i] - (1/n^2) * sum_{ij} exp(T1[i,j])
//   with T0[i] = T1[i,i] + 1   (since xy@W1 = x@Wx + y@Wy)
// so no logsumexp is needed; only the diagonal and a global exp-sum.

#define N_S  1024
#define XD   128
#define HIDD 256
#define JBLK 8   // sample rows per block in proj kernel
#define IBLK 4   // i-rows per block in pair kernel

// ---- Kernel 1: xp^T (+b1) and yp -------------------------------------------
// At[k][j] = sum_d x[j,d] * W1[d,k] + b1[k]       (transposed for coalesced j)
// Yp[i][k] = sum_d y[i,d] * W1[128+d,k]
__global__ __launch_bounds__(256) void proj_kernel(
    const float* __restrict__ x, const float* __restrict__ y,
    const float* __restrict__ W1, const float* __restrict__ b1,
    float* __restrict__ At, float* __restrict__ Yp) {
  const int k  = threadIdx.x;          // hidden index 0..255
  const int r0 = blockIdx.x * JBLK;    // sample base
  const int which = blockIdx.y;        // 0: x -> At, 1: y -> Yp

  __shared__ float s_in[JBLK][XD];
  const float* src = which ? y : x;
  for (int t = k; t < JBLK * XD; t += 256) {
    s_in[t >> 7][t & 127] = src[r0 * XD + t];   // rows are contiguous
  }
  __syncthreads();

  const float* W = W1 + (which ? XD * HIDD : 0);
  float acc[JBLK];
  #pragma unroll
  for (int r = 0; r < JBLK; ++r) acc[r] = 0.f;

  for (int d = 0; d < XD; ++d) {
    const float w = W[d * HIDD + k];           // coalesced across k
    #pragma unroll
    for (int r = 0; r < JBLK; ++r)
      acc[r] = fmaf(s_in[r][d], w, acc[r]);    // LDS broadcast
  }

  if (which) {
    #pragma unroll
    for (int r = 0; r < JBLK; ++r) Yp[(r0 + r) * HIDD + k] = acc[r];
  } else {
    const float bk = b1[k];
    #pragma unroll
    for (int r = 0; r < JBLK; ++r) At[k * N_S + (r0 + r)] = acc[r] + bk;
  }
}

// ---- Kernel 2: pairwise relu-dot, exp-sum, diagonal ------------------------
// Block owns IBLK consecutive i-rows; thread owns 4 consecutive j (float4).
__global__ __launch_bounds__(256) void pair_kernel(
    const float* __restrict__ At, const float* __restrict__ Yp,
    const float* __restrict__ W2, const float* __restrict__ b2,
    double* __restrict__ accum) {   // accum[0]=diag sum, accum[1]=exp sum
  const int tid = threadIdx.x;
  const int i0  = blockIdx.x * IBLK;

  __shared__ float s_yp[IBLK][HIDD];
  __shared__ float s_w2[HIDD];
  #pragma unroll
  for (int ii = 0; ii < IBLK; ++ii)
    s_yp[ii][tid] = Yp[(i0 + ii) * HIDD + tid];
  s_w2[tid] = W2[tid];
  __syncthreads();

  const int j0 = tid * 4;
  float acc[IBLK][4];
  #pragma unroll
  for (int ii = 0; ii < IBLK; ++ii)
    #pragma unroll
    for (int v = 0; v < 4; ++v) acc[ii][v] = 0.f;

  #pragma unroll 4
  for (int k = 0; k < HIDD; ++k) {
    const float4 a = *(const float4*)(At + k * N_S + j0);  // coalesced
    const float  w = s_w2[k];
    #pragma unroll
    for (int ii = 0; ii < IBLK; ++ii) {
      const float c = s_yp[ii][k];                         // LDS broadcast
      acc[ii][0] = fmaf(fmaxf(a.x + c, 0.f), w, acc[ii][0]);
      acc[ii][1] = fmaf(fmaxf(a.y + c, 0.f), w, acc[ii][1]);
      acc[ii][2] = fmaf(fmaxf(a.z + c, 0.f), w, acc[ii][2]);
      acc[ii][3] = fmaf(fmaxf(a.w + c, 0.f), w, acc[ii][3]);
    }
  }

  // epilogue: exp-sum over this thread's 16 pairs; diagonal handling
  const float bb = b2[0] - 1.0f;     // T1 = s + b2 - 1
  float esum = 0.f;
  #pragma unroll
  for (int ii = 0; ii < IBLK; ++ii)
    #pragma unroll
    for (int v = 0; v < 4; ++v)
      esum += __expf(acc[ii][v] + bb);

  // wave reduction (64 lanes), then cross-wave via LDS
  #pragma unroll
  for (int m = 32; m >= 1; m >>= 1) esum += __shfl_xor(esum, m, 64);
  __shared__ float s_part[4];
  const int wave = tid >> 6, lane = tid & 63;
  if (lane == 0) s_part[wave] = esum;
  __syncthreads();
  if (tid == 0) {
    float tot = s_part[0] + s_part[1] + s_part[2] + s_part[3];
    atomicAdd(&accum[1], (double)tot);
  }

  // diagonal: j == i happens only for thread tid == blockIdx.x, v == ii
  if (tid == blockIdx.x) {
    double d = 0.0;
    #pragma unroll
    for (int ii = 0; ii < IBLK; ++ii) d += (double)acc[ii][ii];
    atomicAdd(&accum[0], d);
  }
}

// ---- Kernel 3: finalize ----------------------------------------------------
__global__ void finalize_kernel(const double* __restrict__ accum,
                                const float* __restrict__ b2,
                                float* __restrict__ out) {
  if (threadIdx.x == 0 && blockIdx.x == 0) {
    const double n = (double)N_S;
    const double mean_T0 = accum[0] / n + (double)b2[0];  // T0[i] = s_ii + b2
    const double term2   = accum[1] / (n * n);
    out[0] = (float)(mean_T0 - term2);
  }
}

extern "C" void kernel_launch(void* const* d_in, const int* in_sizes, int n_in,
                              void* d_out, int out_size, void* d_ws, size_t ws_size,
                              hipStream_t stream) {
  const float* x  = (const float*)d_in[0];
  const float* y  = (const float*)d_in[1];
  const float* W1 = (const float*)d_in[2];
  const float* b1 = (const float*)d_in[3];
  const float* W2 = (const float*)d_in[4];
  const float* b2 = (const float*)d_in[5];

  float*  At    = (float*)d_ws;                 // [HIDD][N_S]  (1 MB)
  float*  Yp    = At + HIDD * N_S;              // [N_S][HIDD]  (1 MB)
  double* accum = (double*)(Yp + N_S * HIDD);   // 2 doubles (8-byte aligned)

  hipMemsetAsync(accum, 0, 2 * sizeof(double), stream);

  dim3 g1(N_S / JBLK, 2);
  proj_kernel<<<g1, 256, 0, stream>>>(x, y, W1, b1, At, Yp);
  pair_kernel<<<N_S / IBLK, 256, 0, stream>>>(At, Yp, W2, b2, accum);
  finalize_kernel<<<1, 64, 0, stream>>>(accum, b2, (float*)d_out);
}

// Round 3
// 107.252 us; speedup vs baseline: 1.1168x; 1.1168x over previous
//
#include <hip/hip_runtime.h>

// NWJ lower bound:
//   T1[i,j] = sum_k relu(xp[j,k] + yp[i,k] + b1[k]) * W2[k] + b2 - 1
//   bound   = mean_i T0[i] - (1/n^2) * sum_{ij} exp(T1[i,j])
//   with T0[i] = T1[i,i] + 1   (since xy@W1 = x@Wx + y@Wy)
// No logsumexp needed; only the diagonal and a global exp-sum.

#define N_S   1024
#define XD    128
#define HIDD  256
#define JBLK  16    // sample rows per proj block
#define IBLK  8     // i-rows per pair block
#define JTILE 256   // j columns per pair block (1 per thread)

// ---- Kernel 1: projections --------------------------------------------------
// which=0: At[k][j] = (x@Wx)[j,k] + b1[k]   (transposed via LDS for coalescing)
// which=1: Yp[i][k] = (y@Wy)[i,k]
__global__ __launch_bounds__(256) void proj_kernel(
    const float* __restrict__ x, const float* __restrict__ y,
    const float* __restrict__ W1, const float* __restrict__ b1,
    float* __restrict__ At, float* __restrict__ Yp) {
  const int k     = threadIdx.x;        // hidden index 0..255
  const int which = blockIdx.y;
  const int r0    = blockIdx.x * JBLK;  // sample base

  __shared__ float s_in[JBLK][XD];      // 8 KB
  const float* src = which ? y : x;
  for (int t = k; t < JBLK * XD; t += 256)
    s_in[t >> 7][t & 127] = src[r0 * XD + t];     // rows contiguous, coalesced
  __syncthreads();

  const float* W = W1 + (which ? XD * HIDD : 0);
  float acc[JBLK];
  #pragma unroll
  for (int r = 0; r < JBLK; ++r) acc[r] = 0.f;

  #pragma unroll 4
  for (int d = 0; d < XD; ++d) {
    const float w = W[d * HIDD + k];              // coalesced across k
    #pragma unroll
    for (int r = 0; r < JBLK; ++r)
      acc[r] = fmaf(s_in[r][d], w, acc[r]);       // LDS broadcast
  }

  if (which) {
    #pragma unroll
    for (int r = 0; r < JBLK; ++r) Yp[(r0 + r) * HIDD + k] = acc[r];  // coalesced
  } else {
    // transpose via LDS so global writes are 64B segments, not scattered dwords
    const float bk = b1[k];
    __shared__ float s_t[HIDD][JBLK + 1];         // pad 17 -> conflict-free writes
    #pragma unroll
    for (int r = 0; r < JBLK; ++r) s_t[k][r] = acc[r] + bk;
    __syncthreads();
    const int jj = k & (JBLK - 1);                // 0..15
    const int kk = k >> 4;                        // 0..15
    #pragma unroll
    for (int m = 0; m < JBLK; ++m) {
      const int kr = m * 16 + kk;
      At[kr * N_S + r0 + jj] = s_t[kr][jj];       // 16 consecutive j per k
    }
  }
}

// ---- Kernel 2: pairwise relu-dot, exp-sum, diagonal ------------------------
// Block: IBLK i-rows x JTILE j-cols; thread owns one j, streams k.
// partial[b] = (block exp-sum, block diag-sum)
__global__ __launch_bounds__(256, 2) void pair_kernel(
    const float* __restrict__ At, const float* __restrict__ Yp,
    const float* __restrict__ W2, const float* __restrict__ b2,
    float2* __restrict__ partial) {
  const int tid = threadIdx.x;
  const int ib  = blockIdx.x >> 2;        // 0..127
  const int jt  = blockIdx.x & 3;         // 0..3
  const int i0  = ib * IBLK;
  const int j   = jt * JTILE + tid;

  // one 48B row per k: [0..7] = yp^T (8 i-rows), [8] = w2[k]; rows 16B-aligned
  __shared__ float s_row[HIDD][12];       // 12 KB
  #pragma unroll
  for (int ii = 0; ii < IBLK; ++ii)
    s_row[tid][ii] = Yp[(i0 + ii) * HIDD + tid];  // coalesced global read
  s_row[tid][8] = W2[tid];
  __syncthreads();

  float acc[IBLK];
  #pragma unroll
  for (int ii = 0; ii < IBLK; ++ii) acc[ii] = 0.f;

  const float* ap = At + j;
  #pragma unroll 4
  for (int k = 0; k < HIDD; ++k) {
    const float  a  = ap[k * N_S];                       // coalesced dword
    const float4 y0 = *(const float4*)&s_row[k][0];      // broadcast b128
    const float4 y1 = *(const float4*)&s_row[k][4];      // broadcast b128
    const float  w  = s_row[k][8];                       // broadcast b32
    acc[0] = fmaf(fmaxf(a + y0.x, 0.f), w, acc[0]);
    acc[1] = fmaf(fmaxf(a + y0.y, 0.f), w, acc[1]);
    acc[2] = fmaf(fmaxf(a + y0.z, 0.f), w, acc[2]);
    acc[3] = fmaf(fmaxf(a + y0.w, 0.f), w, acc[3]);
    acc[4] = fmaf(fmaxf(a + y1.x, 0.f), w, acc[4]);
    acc[5] = fmaf(fmaxf(a + y1.y, 0.f), w, acc[5]);
    acc[6] = fmaf(fmaxf(a + y1.z, 0.f), w, acc[6]);
    acc[7] = fmaf(fmaxf(a + y1.w, 0.f), w, acc[7]);
  }

  // epilogue: exp-sum over this thread's 8 pairs + diagonal pick
  const float bb = b2[0] - 1.0f;          // T1 = s + b2 - 1
  float esum = 0.f;
  #pragma unroll
  for (int ii = 0; ii < IBLK; ++ii) esum += __expf(acc[ii] + bb);

  float diag = 0.f;
  const int dd = j - i0;
  #pragma unroll
  for (int ii = 0; ii < IBLK; ++ii)       // compile-time indices (no scratch)
    if (dd == ii) diag = acc[ii];

  // wave reduce both, then cross-wave via LDS, one store per block
  #pragma unroll
  for (int m = 32; m >= 1; m >>= 1) {
    esum += __shfl_xor(esum, m, 64);
    diag += __shfl_xor(diag, m, 64);
  }
  __shared__ float s_es[4], s_dg[4];
  const int wave = tid >> 6, lane = tid & 63;
  if (lane == 0) { s_es[wave] = esum; s_dg[wave] = diag; }
  __syncthreads();
  if (tid == 0)
    partial[blockIdx.x] = make_float2(s_es[0] + s_es[1] + s_es[2] + s_es[3],
                                      s_dg[0] + s_dg[1] + s_dg[2] + s_dg[3]);
}

// ---- Kernel 3: finalize (reduce 512 block partials in f64) -----------------
__global__ __launch_bounds__(256) void finalize_kernel(
    const float2* __restrict__ partial, const float* __restrict__ b2,
    float* __restrict__ out) {
  const int tid = threadIdx.x;
  const float2 p0 = partial[tid];
  const float2 p1 = partial[tid + 256];
  double es = (double)p0.x + (double)p1.x;
  double dg = (double)p0.y + (double)p1.y;
  #pragma unroll
  for (int m = 32; m >= 1; m >>= 1) {
    es += __shfl_xor(es, m, 64);
    dg += __shfl_xor(dg, m, 64);
  }
  __shared__ double s_es[4], s_dg[4];
  const int wave = tid >> 6, lane = tid & 63;
  if (lane == 0) { s_es[wave] = es; s_dg[wave] = dg; }
  __syncthreads();
  if (tid == 0) {
    const double esT = s_es[0] + s_es[1] + s_es[2] + s_es[3];
    const double dgT = s_dg[0] + s_dg[1] + s_dg[2] + s_dg[3];
    const double n = (double)N_S;
    // mean T0 = diag/n + b2 ; term2 = expsum / n^2
    out[0] = (float)(dgT / n + (double)b2[0] - esT / (n * n));
  }
}

extern "C" void kernel_launch(void* const* d_in, const int* in_sizes, int n_in,
                              void* d_out, int out_size, void* d_ws, size_t ws_size,
                              hipStream_t stream) {
  const float* x  = (const float*)d_in[0];
  const float* y  = (const float*)d_in[1];
  const float* W1 = (const float*)d_in[2];
  const float* b1 = (const float*)d_in[3];
  const float* W2 = (const float*)d_in[4];
  const float* b2 = (const float*)d_in[5];

  float*  At      = (float*)d_ws;               // [HIDD][N_S]   1 MB
  float*  Yp      = At + HIDD * N_S;            // [N_S][HIDD]   1 MB
  float2* partial = (float2*)(Yp + N_S * HIDD); // 512 float2    4 KB

  dim3 g1(N_S / JBLK, 2);                       // 64 x 2 blocks
  proj_kernel<<<g1, 256, 0, stream>>>(x, y, W1, b1, At, Yp);
  pair_kernel<<<(N_S / IBLK) * (N_S / JTILE), 256, 0, stream>>>(At, Yp, W2, b2, partial);
  finalize_kernel<<<1, 256, 0, stream>>>(partial, b2, (float*)d_out);
}